// Round 1
// 889.768 us; speedup vs baseline: 3.7375x; 3.7375x over previous
//
#include <hip/hip_runtime.h>
#include <math.h>

#define HD 128

// ---------------------------------------------------------------- zero fill
__global__ void __launch_bounds__(256) zero_kernel(float4* __restrict__ p, long n4) {
  long i = (long)blockIdx.x * blockDim.x + threadIdx.x;
  long stride = (long)gridDim.x * blockDim.x;
  float4 z = make_float4(0.f, 0.f, 0.f, 0.f);
  for (; i < n4; i += stride) p[i] = z;
}

// ------------------------------------------------- sigmoid(x[:2] @ W^T + b)
__global__ void __launch_bounds__(256) sigmoid_gemm(const float* __restrict__ x,
                                                    const float* __restrict__ W,
                                                    const float* __restrict__ b,
                                                    float* __restrict__ SI,
                                                    int nrows) {
  __shared__ float Wl[HD * HD];     // 64 KB
  __shared__ float xs[16 * HD];     // 8 KB
  for (int i = threadIdx.x; i < HD * HD; i += 256) Wl[i] = W[i];
  int row0 = blockIdx.x * 16;
  for (int i = threadIdx.x; i < 16 * HD; i += 256) {
    int r = row0 + (i >> 7);
    xs[i] = (r < nrows) ? x[(long)row0 * HD + i] : 0.f;
  }
  __syncthreads();

  int o = threadIdx.x & (HD - 1);   // output channel 0..127
  int half = threadIdx.x >> 7;      // 0/1 -> rows half*8 .. half*8+7
  float acc[8];
#pragma unroll
  for (int r = 0; r < 8; ++r) acc[r] = 0.f;

#pragma unroll 4
  for (int step = 0; step < HD; ++step) {
    int hh = (step + o) & (HD - 1);
    float wv = Wl[o * HD + hh];
#pragma unroll
    for (int r = 0; r < 8; ++r)
      acc[r] = fmaf(xs[(half * 8 + r) * HD + hh], wv, acc[r]);
  }

  float bb = b[o];
#pragma unroll
  for (int r = 0; r < 8; ++r) {
    int row = row0 + half * 8 + r;
    if (row < nrows) {
      float v = acc[r] + bb;
      SI[(long)row * HD + o] = 1.f / (1.f + __expf(-v));
    }
  }
}

// ------------------------------------------------------------- CSR build
// 1) histogram of destination rows (int atomics on 100K counters)
__global__ void __launch_bounds__(256) hist_rows(const int* __restrict__ rows,
                                                 int* __restrict__ cnt, int n_edges) {
  int i = blockIdx.x * 256 + threadIdx.x;
  int stride = gridDim.x * 256;
  for (; i < n_edges; i += stride) atomicAdd(&cnt[rows[i]], 1);
}

// 2) exclusive scan of counts -> offsets (block-local pass)
#define SCAN_E 2048  // 256 threads x 8 elems
__global__ void __launch_bounds__(256) scan_block(const int* __restrict__ cnt,
                                                  int* __restrict__ off,
                                                  int* __restrict__ bsum, int n) {
  __shared__ int tsum[256];
  int tid = threadIdx.x;
  int base = blockIdx.x * SCAN_E + tid * 8;
  int vals[8];
  int s = 0;
#pragma unroll
  for (int k = 0; k < 8; ++k) {
    int idx = base + k;
    vals[k] = (idx < n) ? cnt[idx] : 0;
    s += vals[k];
  }
  tsum[tid] = s;
  __syncthreads();
  for (int o = 1; o < 256; o <<= 1) {
    int add = (tid >= o) ? tsum[tid - o] : 0;
    __syncthreads();
    tsum[tid] += add;
    __syncthreads();
  }
  int tbase = tsum[tid] - s;  // exclusive base for this thread
  int run = 0;
#pragma unroll
  for (int k = 0; k < 8; ++k) {
    int idx = base + k;
    if (idx < n) off[idx] = tbase + run;
    run += vals[k];
  }
  if (tid == 255) bsum[blockIdx.x] = tsum[255];
}

// 3) scan the (tiny) per-block sums
__global__ void scan_top(int* __restrict__ bsum, int nb) {
  if (threadIdx.x == 0) {
    int acc = 0;
    for (int i = 0; i < nb; ++i) { int v = bsum[i]; bsum[i] = acc; acc += v; }
  }
}

// 4) add block bases; also write the terminal offset
__global__ void __launch_bounds__(256) scan_add(int* __restrict__ off,
                                                const int* __restrict__ bsum,
                                                int n, int n_edges) {
  int base = blockIdx.x * SCAN_E + threadIdx.x * 8;
  int add = bsum[blockIdx.x];
#pragma unroll
  for (int k = 0; k < 8; ++k) {
    int idx = base + k;
    if (idx < n) off[idx] += add;
  }
  if (blockIdx.x == 0 && threadIdx.x == 0) off[n] = n_edges;
}

// 5) bucket the source column of each edge into its row's CSR slot
__global__ void __launch_bounds__(256) fill_csr(const int* __restrict__ rows,
                                                const int* __restrict__ cols,
                                                const int* __restrict__ off,
                                                int* __restrict__ cursor,
                                                int* __restrict__ ecol, int n_edges) {
  int i = blockIdx.x * 256 + threadIdx.x;
  int stride = gridDim.x * 256;
  for (; i < n_edges; i += stride) {
    int r = rows[i];
    int p = atomicAdd(&cursor[r], 1);
    ecol[off[r] + p] = cols[i];
  }
}

// ------------------------------------------------ fused gather + epilogue
// One wave (64 lanes) per node: AI[node] = sum over CSR list of I[col]
// (coalesced 512B/wave reads, no atomics), then dS/dI/dR in registers.
__global__ void __launch_bounds__(256) gather_finalize(const float* __restrict__ S,
                                                       const float* __restrict__ I,
                                                       const float* __restrict__ x3,
                                                       const int* __restrict__ off,
                                                       const int* __restrict__ ecol,
                                                       float* __restrict__ out,
                                                       int n_nodes) {
  int node = blockIdx.x * 4 + (threadIdx.x >> 6);
  if (node >= n_nodes) return;
  int lane = threadIdx.x & 63;

  int beg = off[node], end = off[node + 1];
  float2 acc = make_float2(0.f, 0.f);
  for (int j0 = beg; j0 < end; j0 += 64) {
    int myc = (j0 + lane < end) ? ecol[j0 + lane] : 0;
    int cnt = min(64, end - j0);
    int j = 0;
    for (; j + 1 < cnt; j += 2) {
      int c0 = __shfl(myc, j);
      int c1 = __shfl(myc, j + 1);
      float2 v0 = ((const float2*)(I + (long)c0 * HD))[lane];
      float2 v1 = ((const float2*)(I + (long)c1 * HD))[lane];
      acc.x += v0.x + v1.x;
      acc.y += v0.y + v1.y;
    }
    if (j < cnt) {
      int c0 = __shfl(myc, j);
      float2 v0 = ((const float2*)(I + (long)c0 * HD))[lane];
      acc.x += v0.x;
      acc.y += v0.y;
    }
  }

  float beta  = x3[(long)node * HD + 0];
  float gamma = x3[(long)node * HD + 1];
  float2 s  = ((const float2*)(S + (long)node * HD))[lane];
  float2 ii = ((const float2*)(I + (long)node * HD))[lane];

  float2 dS, dI, dR;
  dS.x = -beta * acc.x * s.x;
  dS.y = -beta * acc.y * s.y;
  dI.x = -dS.x - gamma * ii.x;
  dI.y = -dS.y - gamma * ii.y;
  dR.x = gamma * ii.x;
  dR.y = gamma * ii.y;

  long p = (long)node * (HD / 2) + lane;
  long plane = (long)n_nodes * (HD / 2);
  float2* o = (float2*)out;
  o[p] = dS;
  o[plane + p] = dI;
  o[2 * plane + p] = dR;
}

// ---------------------------------------------------------------- launcher
extern "C" void kernel_launch(void* const* d_in, const int* in_sizes, int n_in,
                              void* d_out, int out_size, void* d_ws, size_t ws_size,
                              hipStream_t stream) {
  const float* x = (const float*)d_in[0];
  const float* W = (const float*)d_in[1];
  const float* b = (const float*)d_in[2];
  const int* rows = (const int*)d_in[3];
  const int* cols = (const int*)d_in[4];
  float* out = (float*)d_out;

  int n_nodes = in_sizes[0] / (4 * HD);
  int n_edges = in_sizes[3];
  int nrows = 2 * n_nodes;

  // workspace layout
  float* S = (float*)d_ws;                       // n_nodes*HD floats
  float* I = S + (long)n_nodes * HD;             // n_nodes*HD floats
  int* ib = (int*)(I + (long)n_nodes * HD);      // int region (16B aligned)
  int npad = n_nodes + 8;
  int* counts  = ib;                             // npad
  int* cursor  = counts + npad;                  // npad
  int* offsets = cursor + npad;                  // npad (needs n_nodes+1)
  int* bsum    = offsets + npad;                 // 64
  int* ecol    = bsum + 64;                      // n_edges

  long n4 = (long)n_nodes * HD / 4;              // float4 per plane
  int zb = (int)((n4 + 255) / 256);

  // zero out plane 3, and counts+cursor (contiguous 2*npad ints)
  zero_kernel<<<zb, 256, 0, stream>>>((float4*)(out + 3 * (long)n_nodes * HD), n4);
  zero_kernel<<<(2 * npad / 4 + 255) / 256, 256, 0, stream>>>((float4*)counts, 2 * npad / 4);

  // S, I = sigmoid(x[:2] @ W^T + b)
  int gblocks = (nrows + 15) / 16;
  sigmoid_gemm<<<gblocks, 256, 0, stream>>>(x, W, b, S, nrows);

  // CSR build
  int eb = min(2048, (n_edges + 255) / 256);
  hist_rows<<<eb, 256, 0, stream>>>(rows, counts, n_edges);
  int nb = (n_nodes + SCAN_E - 1) / SCAN_E;
  scan_block<<<nb, 256, 0, stream>>>(counts, offsets, bsum, n_nodes);
  scan_top<<<1, 64, 0, stream>>>(bsum, nb);
  scan_add<<<nb, 256, 0, stream>>>(offsets, bsum, n_nodes, n_edges);
  fill_csr<<<eb, 256, 0, stream>>>(rows, cols, offsets, cursor, ecol, n_edges);

  // fused gather + epilogue (writes out planes 0,1,2)
  int gfb = (n_nodes + 3) / 4;
  gather_finalize<<<gfb, 256, 0, stream>>>(S, I, x + 3 * (long)n_nodes * HD,
                                           offsets, ecol, out, n_nodes);
}

// Round 2
// 681.641 us; speedup vs baseline: 4.8786x; 1.3053x over previous
//
#include <hip/hip_runtime.h>
#include <math.h>

#define HD 128
#define BM 128

typedef short bf16x8 __attribute__((ext_vector_type(8)));
typedef float f32x4 __attribute__((ext_vector_type(4)));
typedef unsigned short u16;

static __device__ __forceinline__ u16 f2bf(float f) {
  unsigned int u = __float_as_uint(f);
  u += 0x7FFF + ((u >> 16) & 1);   // RNE (inputs are finite, no NaN handling)
  return (u16)(u >> 16);
}
static __device__ __forceinline__ float bf2f(u16 s) {
  return __uint_as_float(((unsigned int)s) << 16);
}

// ---------------------------------------------------------------- zero fill
__global__ void __launch_bounds__(256) zero_kernel(float4* __restrict__ p, long n4) {
  long i = (long)blockIdx.x * blockDim.x + threadIdx.x;
  long stride = (long)gridDim.x * blockDim.x;
  float4 z = make_float4(0.f, 0.f, 0.f, 0.f);
  for (; i < n4; i += stride) p[i] = z;
}

// ------------------------------------------- sigmoid(x[:2] @ W^T + b), MFMA
// Split-bf16: x = xh + xl, W = Wh + Wl (bf16 hi + bf16 residual).
// x@W^T ~= xh@Wh + xl@Wh + xh@Wl  (~16 mantissa bits, error ~1e-4 on logits).
// LDS: Wh/Wl [128][128] bf16 + Xh/Xl [128][128] bf16 = 128 KB, 1 block/CU.
// 16B chunks stored at chunk^(row&15) so staging writes and frag reads are
// <=2-way bank conflicts (free).
__global__ void __launch_bounds__(512) sigmoid_gemm_mfma(
    const float* __restrict__ x, const float* __restrict__ W,
    const float* __restrict__ b, float* __restrict__ SI, int nrows) {
  __shared__ u16 Wh[HD * HD];
  __shared__ u16 Wl[HD * HD];
  __shared__ u16 Xh[BM * HD];
  __shared__ u16 Xl[BM * HD];

  int tid = threadIdx.x;
  int row0 = blockIdx.x * BM;

  // ---- stage W hi/lo (16384 elems = 2048 chunks of 8)
  for (int idx = tid; idx < HD * (HD / 8); idx += 512) {
    int r = idx >> 4;        // W row (= output channel o)
    int c = idx & 15;        // 8-elem chunk within row
    const float4* src = (const float4*)(W + r * HD + c * 8);
    float4 a0 = src[0], a1 = src[1];
    float f[8] = {a0.x, a0.y, a0.z, a0.w, a1.x, a1.y, a1.z, a1.w};
    union { u16 s[8]; uint4 v; } Ph, Pl;
#pragma unroll
    for (int i = 0; i < 8; ++i) {
      u16 h = f2bf(f[i]);
      Ph.s[i] = h;
      Pl.s[i] = f2bf(f[i] - bf2f(h));
    }
    int dst = r * HD + ((c ^ (r & 15)) << 3);
    *(uint4*)&Wh[dst] = Ph.v;
    *(uint4*)&Wl[dst] = Pl.v;
  }

  // ---- stage X hi/lo (BM rows)
  for (int idx = tid; idx < BM * (HD / 8); idx += 512) {
    int r = idx >> 4;
    int c = idx & 15;
    int grow = row0 + r;
    float f[8] = {0.f, 0.f, 0.f, 0.f, 0.f, 0.f, 0.f, 0.f};
    if (grow < nrows) {
      const float4* src = (const float4*)(x + (long)grow * HD + c * 8);
      float4 a0 = src[0], a1 = src[1];
      f[0] = a0.x; f[1] = a0.y; f[2] = a0.z; f[3] = a0.w;
      f[4] = a1.x; f[5] = a1.y; f[6] = a1.z; f[7] = a1.w;
    }
    union { u16 s[8]; uint4 v; } Ph, Pl;
#pragma unroll
    for (int i = 0; i < 8; ++i) {
      u16 h = f2bf(f[i]);
      Ph.s[i] = h;
      Pl.s[i] = f2bf(f[i] - bf2f(h));
    }
    int dst = r * HD + ((c ^ (r & 15)) << 3);
    *(uint4*)&Xh[dst] = Ph.v;
    *(uint4*)&Xl[dst] = Pl.v;
  }
  __syncthreads();

  // ---- compute: wave w owns rows 16w..16w+15 (within tile), all 8 col-tiles
  int w = tid >> 6;
  int l = tid & 63;
  int lr = l & 15;   // A row-in-tile / B,D col-in-tile
  int lk = l >> 4;   // k-block (8 elems each)
  int arow = w * 16 + lr;

  bf16x8 ah[4], al[4];
#pragma unroll
  for (int s = 0; s < 4; ++s) {
    int ca = (((s * 4 + lk) ^ lr) << 3);   // arow&15 == lr
    ah[s] = *(const bf16x8*)&Xh[arow * HD + ca];
    al[s] = *(const bf16x8*)&Xl[arow * HD + ca];
  }

#pragma unroll
  for (int ct = 0; ct < 8; ++ct) {
    int col = ct * 16 + lr;
    f32x4 acc = {0.f, 0.f, 0.f, 0.f};
#pragma unroll
    for (int s = 0; s < 4; ++s) {
      int cb = (((s * 4 + lk) ^ lr) << 3);  // col&15 == lr
      bf16x8 bh = *(const bf16x8*)&Wh[col * HD + cb];
      bf16x8 bl = *(const bf16x8*)&Wl[col * HD + cb];
      acc = __builtin_amdgcn_mfma_f32_16x16x32_bf16(ah[s], bh, acc, 0, 0, 0);
      acc = __builtin_amdgcn_mfma_f32_16x16x32_bf16(al[s], bh, acc, 0, 0, 0);
      acc = __builtin_amdgcn_mfma_f32_16x16x32_bf16(ah[s], bl, acc, 0, 0, 0);
    }
    float bb = b[col];
#pragma unroll
    for (int j = 0; j < 4; ++j) {
      int grow = row0 + w * 16 + lk * 4 + j;   // D: row = 4*(l>>4)+j
      if (grow < nrows) {
        float v = acc[j] + bb;
        SI[(long)grow * HD + col] = 1.f / (1.f + __expf(-v));
      }
    }
  }
}

// ------------------------------------------------------------- CSR build
__global__ void __launch_bounds__(256) hist_rows(const int* __restrict__ rows,
                                                 int* __restrict__ cnt, int n_edges) {
  int i = blockIdx.x * 256 + threadIdx.x;
  int stride = gridDim.x * 256;
  for (; i < n_edges; i += stride) atomicAdd(&cnt[rows[i]], 1);
}

#define SCAN_E 2048  // 256 threads x 8 elems
__global__ void __launch_bounds__(256) scan_block(const int* __restrict__ cnt,
                                                  int* __restrict__ off,
                                                  int* __restrict__ bsum, int n) {
  __shared__ int tsum[256];
  int tid = threadIdx.x;
  int base = blockIdx.x * SCAN_E + tid * 8;
  int vals[8];
  int s = 0;
#pragma unroll
  for (int k = 0; k < 8; ++k) {
    int idx = base + k;
    vals[k] = (idx < n) ? cnt[idx] : 0;
    s += vals[k];
  }
  tsum[tid] = s;
  __syncthreads();
  for (int o = 1; o < 256; o <<= 1) {
    int add = (tid >= o) ? tsum[tid - o] : 0;
    __syncthreads();
    tsum[tid] += add;
    __syncthreads();
  }
  int tbase = tsum[tid] - s;
  int run = 0;
#pragma unroll
  for (int k = 0; k < 8; ++k) {
    int idx = base + k;
    if (idx < n) off[idx] = tbase + run;
    run += vals[k];
  }
  if (tid == 255) bsum[blockIdx.x] = tsum[255];
}

__global__ void scan_top(int* __restrict__ bsum, int nb) {
  if (threadIdx.x == 0) {
    int acc = 0;
    for (int i = 0; i < nb; ++i) { int v = bsum[i]; bsum[i] = acc; acc += v; }
  }
}

__global__ void __launch_bounds__(256) scan_add(int* __restrict__ off,
                                                const int* __restrict__ bsum,
                                                int n, int n_edges) {
  int base = blockIdx.x * SCAN_E + threadIdx.x * 8;
  int add = bsum[blockIdx.x];
#pragma unroll
  for (int k = 0; k < 8; ++k) {
    int idx = base + k;
    if (idx < n) off[idx] += add;
  }
  if (blockIdx.x == 0 && threadIdx.x == 0) off[n] = n_edges;
}

__global__ void __launch_bounds__(256) fill_csr(const int* __restrict__ rows,
                                                const int* __restrict__ cols,
                                                const int* __restrict__ off,
                                                int* __restrict__ cursor,
                                                int* __restrict__ ecol, int n_edges) {
  int i = blockIdx.x * 256 + threadIdx.x;
  int stride = gridDim.x * 256;
  for (; i < n_edges; i += stride) {
    int r = rows[i];
    int p = atomicAdd(&cursor[r], 1);
    ecol[off[r] + p] = cols[i];
  }
}

// ------------------------------------------------ fused gather + epilogue
__global__ void __launch_bounds__(256) gather_finalize(const float* __restrict__ S,
                                                       const float* __restrict__ I,
                                                       const float* __restrict__ x3,
                                                       const int* __restrict__ off,
                                                       const int* __restrict__ ecol,
                                                       float* __restrict__ out,
                                                       int n_nodes) {
  int node = blockIdx.x * 4 + (threadIdx.x >> 6);
  if (node >= n_nodes) return;
  int lane = threadIdx.x & 63;

  int beg = off[node], end = off[node + 1];
  float2 acc = make_float2(0.f, 0.f);
  for (int j0 = beg; j0 < end; j0 += 64) {
    int myc = (j0 + lane < end) ? ecol[j0 + lane] : 0;
    int cnt = min(64, end - j0);
    int j = 0;
    for (; j + 3 < cnt; j += 4) {
      int c0 = __shfl(myc, j);
      int c1 = __shfl(myc, j + 1);
      int c2 = __shfl(myc, j + 2);
      int c3 = __shfl(myc, j + 3);
      float2 v0 = ((const float2*)(I + (long)c0 * HD))[lane];
      float2 v1 = ((const float2*)(I + (long)c1 * HD))[lane];
      float2 v2 = ((const float2*)(I + (long)c2 * HD))[lane];
      float2 v3 = ((const float2*)(I + (long)c3 * HD))[lane];
      acc.x += (v0.x + v1.x) + (v2.x + v3.x);
      acc.y += (v0.y + v1.y) + (v2.y + v3.y);
    }
    for (; j < cnt; ++j) {
      int c0 = __shfl(myc, j);
      float2 v0 = ((const float2*)(I + (long)c0 * HD))[lane];
      acc.x += v0.x;
      acc.y += v0.y;
    }
  }

  float beta  = x3[(long)node * HD + 0];
  float gamma = x3[(long)node * HD + 1];
  float2 s  = ((const float2*)(S + (long)node * HD))[lane];
  float2 ii = ((const float2*)(I + (long)node * HD))[lane];

  float2 dS, dI, dR;
  dS.x = -beta * acc.x * s.x;
  dS.y = -beta * acc.y * s.y;
  dI.x = -dS.x - gamma * ii.x;
  dI.y = -dS.y - gamma * ii.y;
  dR.x = gamma * ii.x;
  dR.y = gamma * ii.y;

  long p = (long)node * (HD / 2) + lane;
  long plane = (long)n_nodes * (HD / 2);
  float2* o = (float2*)out;
  o[p] = dS;
  o[plane + p] = dI;
  o[2 * plane + p] = dR;
}

// ---------------------------------------------------------------- launcher
extern "C" void kernel_launch(void* const* d_in, const int* in_sizes, int n_in,
                              void* d_out, int out_size, void* d_ws, size_t ws_size,
                              hipStream_t stream) {
  const float* x = (const float*)d_in[0];
  const float* W = (const float*)d_in[1];
  const float* b = (const float*)d_in[2];
  const int* rows = (const int*)d_in[3];
  const int* cols = (const int*)d_in[4];
  float* out = (float*)d_out;

  int n_nodes = in_sizes[0] / (4 * HD);
  int n_edges = in_sizes[3];
  int nrows = 2 * n_nodes;

  // workspace layout
  float* S = (float*)d_ws;                       // n_nodes*HD floats
  float* I = S + (long)n_nodes * HD;             // n_nodes*HD floats
  int* ib = (int*)(I + (long)n_nodes * HD);      // int region (16B aligned)
  int npad = n_nodes + 8;
  int* counts  = ib;                             // npad
  int* cursor  = counts + npad;                  // npad
  int* offsets = cursor + npad;                  // npad (needs n_nodes+1)
  int* bsum    = offsets + npad;                 // 64
  int* ecol    = bsum + 64;                      // n_edges

  long n4 = (long)n_nodes * HD / 4;              // float4 per plane
  int zb = (int)((n4 + 255) / 256);

  // zero out plane 3, and counts+cursor (contiguous 2*npad ints)
  zero_kernel<<<zb, 256, 0, stream>>>((float4*)(out + 3 * (long)n_nodes * HD), n4);
  zero_kernel<<<(2 * npad / 4 + 255) / 256, 256, 0, stream>>>((float4*)counts, 2 * npad / 4);

  // S, I = sigmoid(x[:2] @ W^T + b) via split-bf16 MFMA
  int gblocks = (nrows + BM - 1) / BM;
  sigmoid_gemm_mfma<<<gblocks, 512, 0, stream>>>(x, W, b, S, nrows);

  // CSR build
  int eb = min(2048, (n_edges + 255) / 256);
  hist_rows<<<eb, 256, 0, stream>>>(rows, counts, n_edges);
  int nb = (n_nodes + SCAN_E - 1) / SCAN_E;
  scan_block<<<nb, 256, 0, stream>>>(counts, offsets, bsum, n_nodes);
  scan_top<<<1, 64, 0, stream>>>(bsum, nb);
  scan_add<<<nb, 256, 0, stream>>>(offsets, bsum, n_nodes, n_edges);
  fill_csr<<<eb, 256, 0, stream>>>(rows, cols, offsets, cursor, ecol, n_edges);

  // fused gather + epilogue (writes out planes 0,1,2)
  int gfb = (n_nodes + 3) / 4;
  gather_finalize<<<gfb, 256, 0, stream>>>(S, I, x + 3 * (long)n_nodes * HD,
                                           offsets, ecol, out, n_nodes);
}

// Round 3
// 621.437 us; speedup vs baseline: 5.3513x; 1.0969x over previous
//
#include <hip/hip_runtime.h>
#include <math.h>

#define HD 128
#define BM 128   // rows per gemm block (8 waves x 16 rows)

typedef short bf16x8 __attribute__((ext_vector_type(8)));
typedef float f32x4 __attribute__((ext_vector_type(4)));
typedef unsigned short u16;

static __device__ __forceinline__ u16 f2bf(float f) {
  unsigned int u = __float_as_uint(f);
  u += 0x7FFF + ((u >> 16) & 1);   // RNE (inputs finite)
  return (u16)(u >> 16);
}
static __device__ __forceinline__ float bf2f(u16 s) {
  return __uint_as_float(((unsigned int)s) << 16);
}

// ---------------------------------------------------------------- zero fill
__global__ void __launch_bounds__(256) zero_kernel(float4* __restrict__ p, long n4) {
  long i = (long)blockIdx.x * blockDim.x + threadIdx.x;
  long stride = (long)gridDim.x * blockDim.x;
  float4 z = make_float4(0.f, 0.f, 0.f, 0.f);
  for (; i < n4; i += stride) p[i] = z;
}

// -------------------------------- fused: sigmoid-GEMM (MFMA) || edge hist
// Blocks [0, gblocks): SI = sigmoid(x[:2] @ W^T + b) via split-bf16 MFMA.
//   W hi/lo staged in 64 KB LDS (2 blocks/CU); A-fragments built from global
//   directly in registers (no X LDS, no per-tile sync).
// Blocks [gblocks, gridDim): histogram of edge destination rows.
__global__ void __launch_bounds__(512, 4) gemm_hist(
    const float* __restrict__ x, const float* __restrict__ W,
    const float* __restrict__ b, float* __restrict__ SI, int nrows,
    const int* __restrict__ rows, int* __restrict__ counts, int n_edges,
    int gblocks) {
  __shared__ u16 Wh[HD * HD];   // 32 KB
  __shared__ u16 Wl[HD * HD];   // 32 KB

  int tid = threadIdx.x;
  if (blockIdx.x >= gblocks) {
    // ---------------- histogram branch
    int i = (blockIdx.x - gblocks) * 512 + tid;
    int stride = (gridDim.x - gblocks) * 512;
    for (; i < n_edges; i += stride) atomicAdd(&counts[rows[i]], 1);
    return;
  }

  // ---------------- gemm branch
  // stage W hi/lo: 2048 chunks of 8 floats; chunk stored at c^(r&15) so both
  // staging writes and fragment reads are <=2-way bank conflicts (free).
  for (int idx = tid; idx < HD * (HD / 8); idx += 512) {
    int r = idx >> 4;
    int c = idx & 15;
    const float4* src = (const float4*)(W + r * HD + c * 8);
    float4 a0 = src[0], a1 = src[1];
    float f[8] = {a0.x, a0.y, a0.z, a0.w, a1.x, a1.y, a1.z, a1.w};
    union { u16 s[8]; uint4 v; } Ph, Pl;
#pragma unroll
    for (int i = 0; i < 8; ++i) {
      u16 h = f2bf(f[i]);
      Ph.s[i] = h;
      Pl.s[i] = f2bf(f[i] - bf2f(h));
    }
    int dst = r * HD + ((c ^ (r & 15)) << 3);
    *(uint4*)&Wh[dst] = Ph.v;
    *(uint4*)&Wl[dst] = Pl.v;
  }
  __syncthreads();

  int w = tid >> 6;
  int l = tid & 63;
  int lr = l & 15;   // A row-in-tile / B,D col-in-tile
  int lk = l >> 4;   // k-chunk quarter
  int rbase = blockIdx.x * BM + w * 16;
  int arow = rbase + lr;
  bool rowok = arow < nrows;

  // A-fragments (hi/lo) straight from global: lane reads 32B at k-chunk s*4+lk
  bf16x8 ah[4], al[4];
#pragma unroll
  for (int s = 0; s < 4; ++s) {
    float f[8] = {0.f, 0.f, 0.f, 0.f, 0.f, 0.f, 0.f, 0.f};
    if (rowok) {
      const float4* src = (const float4*)(x + (long)arow * HD + (s * 4 + lk) * 8);
      float4 a0 = src[0], a1 = src[1];
      f[0] = a0.x; f[1] = a0.y; f[2] = a0.z; f[3] = a0.w;
      f[4] = a1.x; f[5] = a1.y; f[6] = a1.z; f[7] = a1.w;
    }
    union { u16 s16[8]; bf16x8 v; } Ph, Pl;
#pragma unroll
    for (int i = 0; i < 8; ++i) {
      u16 h = f2bf(f[i]);
      Ph.s16[i] = h;
      Pl.s16[i] = f2bf(f[i] - bf2f(h));
    }
    ah[s] = Ph.v;
    al[s] = Pl.v;
  }

#pragma unroll
  for (int ct = 0; ct < 8; ++ct) {
    int col = ct * 16 + lr;
    f32x4 acc = {0.f, 0.f, 0.f, 0.f};
#pragma unroll
    for (int s = 0; s < 4; ++s) {
      int cb = ((s * 4 + lk) ^ lr) << 3;
      bf16x8 bh = *(const bf16x8*)&Wh[col * HD + cb];
      bf16x8 bl = *(const bf16x8*)&Wl[col * HD + cb];
      acc = __builtin_amdgcn_mfma_f32_16x16x32_bf16(ah[s], bh, acc, 0, 0, 0);
      acc = __builtin_amdgcn_mfma_f32_16x16x32_bf16(al[s], bh, acc, 0, 0, 0);
      acc = __builtin_amdgcn_mfma_f32_16x16x32_bf16(ah[s], bl, acc, 0, 0, 0);
    }
    float bb = b[col];
#pragma unroll
    for (int j = 0; j < 4; ++j) {
      int grow = rbase + lk * 4 + j;   // D: row = 4*(l>>4)+j, col = lane&15
      if (grow < nrows) {
        float v = acc[j] + bb;
        SI[(long)grow * HD + col] = 1.f / (1.f + __expf(-v));
      }
    }
  }
}

// ------------------------------------------------------------- CSR build
#define SCAN_E 2048  // 256 threads x 8 elems
__global__ void __launch_bounds__(256) scan_block(const int* __restrict__ cnt,
                                                  int* __restrict__ off,
                                                  int* __restrict__ bsum, int n) {
  __shared__ int tsum[256];
  int tid = threadIdx.x;
  int base = blockIdx.x * SCAN_E + tid * 8;
  int vals[8];
  int s = 0;
#pragma unroll
  for (int k = 0; k < 8; ++k) {
    int idx = base + k;
    vals[k] = (idx < n) ? cnt[idx] : 0;
    s += vals[k];
  }
  tsum[tid] = s;
  __syncthreads();
  for (int o = 1; o < 256; o <<= 1) {
    int add = (tid >= o) ? tsum[tid - o] : 0;
    __syncthreads();
    tsum[tid] += add;
    __syncthreads();
  }
  int tbase = tsum[tid] - s;
  int run = 0;
#pragma unroll
  for (int k = 0; k < 8; ++k) {
    int idx = base + k;
    if (idx < n) off[idx] = tbase + run;
    run += vals[k];
  }
  if (tid == 255) bsum[blockIdx.x] = tsum[255];
}

// parallel scan of per-block sums (nb <= 256; serial fallback otherwise)
__global__ void __launch_bounds__(256) scan_top(int* __restrict__ bsum, int nb) {
  __shared__ int sh[256];
  int tid = threadIdx.x;
  if (nb <= 256) {
    int v = (tid < nb) ? bsum[tid] : 0;
    sh[tid] = v;
    __syncthreads();
    for (int o = 1; o < 256; o <<= 1) {
      int add = (tid >= o) ? sh[tid - o] : 0;
      __syncthreads();
      sh[tid] += add;
      __syncthreads();
    }
    if (tid < nb) bsum[tid] = sh[tid] - v;  // exclusive
  } else if (tid == 0) {
    int acc = 0;
    for (int i = 0; i < nb; ++i) { int v = bsum[i]; bsum[i] = acc; acc += v; }
  }
}

__global__ void __launch_bounds__(256) scan_add(int* __restrict__ off,
                                                const int* __restrict__ bsum,
                                                int n, int n_edges) {
  int base = blockIdx.x * SCAN_E + threadIdx.x * 8;
  int add = bsum[blockIdx.x];
#pragma unroll
  for (int k = 0; k < 8; ++k) {
    int idx = base + k;
    if (idx < n) off[idx] += add;
  }
  if (blockIdx.x == 0 && threadIdx.x == 0) off[n] = n_edges;
}

__global__ void __launch_bounds__(256) fill_csr(const int* __restrict__ rows,
                                                const int* __restrict__ cols,
                                                const int* __restrict__ off,
                                                int* __restrict__ cursor,
                                                int* __restrict__ ecol, int n_edges) {
  int i = blockIdx.x * 256 + threadIdx.x;
  int stride = gridDim.x * 256;
  for (; i < n_edges; i += stride) {
    int r = rows[i];
    int p = atomicAdd(&cursor[r], 1);
    ecol[off[r] + p] = cols[i];
  }
}

// ------------------------------------------------ fused gather + epilogue
// One wave per node: AI = sum of I[col] over CSR list (coalesced, no
// atomics); dS/dI/dR in registers; plane 3 zeroed here too.
__global__ void __launch_bounds__(256) gather_finalize(const float* __restrict__ S,
                                                       const float* __restrict__ I,
                                                       const float* __restrict__ x3,
                                                       const int* __restrict__ off,
                                                       const int* __restrict__ ecol,
                                                       float* __restrict__ out,
                                                       int n_nodes) {
  int node = blockIdx.x * 4 + (threadIdx.x >> 6);
  if (node >= n_nodes) return;
  int lane = threadIdx.x & 63;

  int beg = off[node], end = off[node + 1];
  float2 acc = make_float2(0.f, 0.f);
  for (int j0 = beg; j0 < end; j0 += 64) {
    int myc = (j0 + lane < end) ? ecol[j0 + lane] : 0;
    int cnt = min(64, end - j0);
    int j = 0;
    for (; j + 3 < cnt; j += 4) {
      int c0 = __shfl(myc, j);
      int c1 = __shfl(myc, j + 1);
      int c2 = __shfl(myc, j + 2);
      int c3 = __shfl(myc, j + 3);
      float2 v0 = ((const float2*)(I + (long)c0 * HD))[lane];
      float2 v1 = ((const float2*)(I + (long)c1 * HD))[lane];
      float2 v2 = ((const float2*)(I + (long)c2 * HD))[lane];
      float2 v3 = ((const float2*)(I + (long)c3 * HD))[lane];
      acc.x += (v0.x + v1.x) + (v2.x + v3.x);
      acc.y += (v0.y + v1.y) + (v2.y + v3.y);
    }
    for (; j < cnt; ++j) {
      int c0 = __shfl(myc, j);
      float2 v0 = ((const float2*)(I + (long)c0 * HD))[lane];
      acc.x += v0.x;
      acc.y += v0.y;
    }
  }

  float beta  = x3[(long)node * HD + 0];
  float gamma = x3[(long)node * HD + 1];
  float2 s  = ((const float2*)(S + (long)node * HD))[lane];
  float2 ii = ((const float2*)(I + (long)node * HD))[lane];

  float2 dS, dI, dR;
  dS.x = -beta * acc.x * s.x;
  dS.y = -beta * acc.y * s.y;
  dI.x = -dS.x - gamma * ii.x;
  dI.y = -dS.y - gamma * ii.y;
  dR.x = gamma * ii.x;
  dR.y = gamma * ii.y;

  long p = (long)node * (HD / 2) + lane;
  long plane = (long)n_nodes * (HD / 2);
  float2* o = (float2*)out;
  o[p] = dS;
  o[plane + p] = dI;
  o[2 * plane + p] = dR;
  o[3 * plane + p] = make_float2(0.f, 0.f);   // zero plane 3 here
}

// ---------------------------------------------------------------- launcher
extern "C" void kernel_launch(void* const* d_in, const int* in_sizes, int n_in,
                              void* d_out, int out_size, void* d_ws, size_t ws_size,
                              hipStream_t stream) {
  const float* x = (const float*)d_in[0];
  const float* W = (const float*)d_in[1];
  const float* b = (const float*)d_in[2];
  const int* rows = (const int*)d_in[3];
  const int* cols = (const int*)d_in[4];
  float* out = (float*)d_out;

  int n_nodes = in_sizes[0] / (4 * HD);
  int n_edges = in_sizes[3];
  int nrows = 2 * n_nodes;

  // workspace layout
  float* S = (float*)d_ws;                       // n_nodes*HD floats
  float* I = S + (long)n_nodes * HD;             // n_nodes*HD floats
  int* ib = (int*)(I + (long)n_nodes * HD);      // int region (16B aligned)
  int npad = (n_nodes + 11) & ~3;                // >= n_nodes+8, mult of 4
  int* counts  = ib;                             // npad
  int* cursor  = counts + npad;                  // npad
  int* offsets = cursor + npad;                  // npad (needs n_nodes+1)
  int* bsum    = offsets + npad;                 // 256
  int* ecol    = bsum + 256;                     // n_edges

  // zero counts+cursor (contiguous 2*npad ints)
  zero_kernel<<<(2 * npad / 4 + 255) / 256, 256, 0, stream>>>(
      (float4*)counts, 2 * npad / 4);

  // fused: SI = sigmoid(x[:2] @ W^T + b)  ||  hist of rows
  int gblocks = (nrows + BM - 1) / BM;
  int hblocks = 256;
  gemm_hist<<<gblocks + hblocks, 512, 0, stream>>>(x, W, b, S, nrows,
                                                   rows, counts, n_edges, gblocks);

  // scan counts -> offsets
  int nb = (n_nodes + SCAN_E - 1) / SCAN_E;
  scan_block<<<nb, 256, 0, stream>>>(counts, offsets, bsum, n_nodes);
  scan_top<<<1, 256, 0, stream>>>(bsum, nb);
  scan_add<<<nb, 256, 0, stream>>>(offsets, bsum, n_nodes, n_edges);

  // bucket edges
  int eb = min(2048, (n_edges + 255) / 256);
  fill_csr<<<eb, 256, 0, stream>>>(rows, cols, offsets, cursor, ecol, n_edges);

  // fused gather + epilogue (writes all 4 out planes)
  int gfb = (n_nodes + 3) / 4;
  gather_finalize<<<gfb, 256, 0, stream>>>(S, I, x + 3 * (long)n_nodes * HD,
                                           offsets, ecol, out, n_nodes);
}

// Round 4
// 602.404 us; speedup vs baseline: 5.5204x; 1.0316x over previous
//
#include <hip/hip_runtime.h>
#include <math.h>

#define HD 128
#define BM 128   // rows per gemm block (8 waves x 16 rows)

typedef short bf16x8 __attribute__((ext_vector_type(8)));
typedef float f32x4 __attribute__((ext_vector_type(4)));
typedef unsigned short u16;

static __device__ __forceinline__ u16 f2bf(float f) {
  unsigned int u = __float_as_uint(f);
  u += 0x7FFF + ((u >> 16) & 1);   // RNE (inputs finite)
  return (u16)(u >> 16);
}
static __device__ __forceinline__ float bf2f(u16 s) {
  return __uint_as_float(((unsigned int)s) << 16);
}

// ---------------------------------------------------------------- zero fill
__global__ void __launch_bounds__(256) zero_kernel(float4* __restrict__ p, long n4) {
  long i = (long)blockIdx.x * blockDim.x + threadIdx.x;
  long stride = (long)gridDim.x * blockDim.x;
  float4 z = make_float4(0.f, 0.f, 0.f, 0.f);
  for (; i < n4; i += stride) p[i] = z;
}

// ----------------------------------------------------------- edge histogram
__global__ void __launch_bounds__(256) hist_rows(const int* __restrict__ rows,
                                                 int* __restrict__ cnt, int n_edges) {
  int i = blockIdx.x * 256 + threadIdx.x;
  int stride = gridDim.x * 256;
  for (; i < n_edges; i += stride) atomicAdd(&cnt[rows[i]], 1);
}

// ------------------------------------------------------------- CSR scan
#define SCAN_E 2048  // 256 threads x 8 elems
__global__ void __launch_bounds__(256) scan_block(const int* __restrict__ cnt,
                                                  int* __restrict__ off,
                                                  int* __restrict__ bsum, int n) {
  __shared__ int tsum[256];
  int tid = threadIdx.x;
  int base = blockIdx.x * SCAN_E + tid * 8;
  int vals[8];
  int s = 0;
#pragma unroll
  for (int k = 0; k < 8; ++k) {
    int idx = base + k;
    vals[k] = (idx < n) ? cnt[idx] : 0;
    s += vals[k];
  }
  tsum[tid] = s;
  __syncthreads();
  for (int o = 1; o < 256; o <<= 1) {
    int add = (tid >= o) ? tsum[tid - o] : 0;
    __syncthreads();
    tsum[tid] += add;
    __syncthreads();
  }
  int tbase = tsum[tid] - s;
  int run = 0;
#pragma unroll
  for (int k = 0; k < 8; ++k) {
    int idx = base + k;
    if (idx < n) off[idx] = tbase + run;
    run += vals[k];
  }
  if (tid == 255) bsum[blockIdx.x] = tsum[255];  // raw block total
}

// adds global base (computed in-block from raw bsum; nb<=64 so serial is free)
__global__ void __launch_bounds__(256) scan_add(int* __restrict__ off,
                                                const int* __restrict__ bsum,
                                                int nb, int n, int n_edges) {
  __shared__ int sAdd;
  if (threadIdx.x == 0) {
    int acc = 0;
    for (int i = 0; i < (int)blockIdx.x; ++i) acc += bsum[i];
    sAdd = acc;
  }
  __syncthreads();
  int add = sAdd;
  int base = blockIdx.x * SCAN_E + threadIdx.x * 8;
#pragma unroll
  for (int k = 0; k < 8; ++k) {
    int idx = base + k;
    if (idx < n) off[idx] += add;
  }
  if (blockIdx.x == 0 && threadIdx.x == 0) off[n] = n_edges;
}

// ----------------------- fused: CSR fill (first) || sigmoid-GEMM (MFMA)
// Blocks [0, fblocks): bucket edge cols into CSR slots (atomic cursor).
// Blocks [fblocks, ...): SI = sigmoid(x[:2] @ W^T + b), split-bf16 MFMA,
//   W hi/lo in 64 KB LDS, A-fragments built from global in registers.
// Fill blocks are first so they start immediately; the two workloads
// (atomic/latency vs LDS/MFMA) co-schedule on shared CUs.
__global__ void __launch_bounds__(512, 4) fill_gemm(
    const float* __restrict__ x, const float* __restrict__ W,
    const float* __restrict__ b, float* __restrict__ SI, int nrows,
    const int* __restrict__ rows, const int* __restrict__ cols,
    const int* __restrict__ off, int* __restrict__ cursor,
    int* __restrict__ ecol, int n_edges, int fblocks) {
  __shared__ u16 Wh[HD * HD];   // 32 KB
  __shared__ u16 Wl[HD * HD];   // 32 KB

  int tid = threadIdx.x;
  if (blockIdx.x < fblocks) {
    // ---------------- CSR fill branch
    int i = blockIdx.x * 512 + tid;
    int stride = fblocks * 512;
    for (; i < n_edges; i += stride) {
      int r = rows[i];
      int p = atomicAdd(&cursor[r], 1);
      ecol[off[r] + p] = cols[i];
    }
    return;
  }

  // ---------------- gemm branch
  for (int idx = tid; idx < HD * (HD / 8); idx += 512) {
    int r = idx >> 4;
    int c = idx & 15;
    const float4* src = (const float4*)(W + r * HD + c * 8);
    float4 a0 = src[0], a1 = src[1];
    float f[8] = {a0.x, a0.y, a0.z, a0.w, a1.x, a1.y, a1.z, a1.w};
    union { u16 s[8]; uint4 v; } Ph, Pl;
#pragma unroll
    for (int i = 0; i < 8; ++i) {
      u16 h = f2bf(f[i]);
      Ph.s[i] = h;
      Pl.s[i] = f2bf(f[i] - bf2f(h));
    }
    int dst = r * HD + ((c ^ (r & 15)) << 3);
    *(uint4*)&Wh[dst] = Ph.v;
    *(uint4*)&Wl[dst] = Pl.v;
  }
  __syncthreads();

  int w = tid >> 6;
  int l = tid & 63;
  int lr = l & 15;   // A row-in-tile / B,D col-in-tile
  int lk = l >> 4;   // k-chunk quarter
  int rbase = (blockIdx.x - fblocks) * BM + w * 16;
  int arow = rbase + lr;
  bool rowok = arow < nrows;

  bf16x8 ah[4], al[4];
#pragma unroll
  for (int s = 0; s < 4; ++s) {
    float f[8] = {0.f, 0.f, 0.f, 0.f, 0.f, 0.f, 0.f, 0.f};
    if (rowok) {
      const float4* src = (const float4*)(x + (long)arow * HD + (s * 4 + lk) * 8);
      float4 a0 = src[0], a1 = src[1];
      f[0] = a0.x; f[1] = a0.y; f[2] = a0.z; f[3] = a0.w;
      f[4] = a1.x; f[5] = a1.y; f[6] = a1.z; f[7] = a1.w;
    }
    union { u16 s16[8]; bf16x8 v; } Ph, Pl;
#pragma unroll
    for (int i = 0; i < 8; ++i) {
      u16 h = f2bf(f[i]);
      Ph.s16[i] = h;
      Pl.s16[i] = f2bf(f[i] - bf2f(h));
    }
    ah[s] = Ph.v;
    al[s] = Pl.v;
  }

#pragma unroll
  for (int ct = 0; ct < 8; ++ct) {
    int col = ct * 16 + lr;
    f32x4 acc = {0.f, 0.f, 0.f, 0.f};
#pragma unroll
    for (int s = 0; s < 4; ++s) {
      int cb = ((s * 4 + lk) ^ lr) << 3;
      bf16x8 bh = *(const bf16x8*)&Wh[col * HD + cb];
      bf16x8 bl = *(const bf16x8*)&Wl[col * HD + cb];
      acc = __builtin_amdgcn_mfma_f32_16x16x32_bf16(ah[s], bh, acc, 0, 0, 0);
      acc = __builtin_amdgcn_mfma_f32_16x16x32_bf16(al[s], bh, acc, 0, 0, 0);
      acc = __builtin_amdgcn_mfma_f32_16x16x32_bf16(ah[s], bl, acc, 0, 0, 0);
    }
    float bb = b[col];
#pragma unroll
    for (int j = 0; j < 4; ++j) {
      int grow = rbase + lk * 4 + j;   // D: row = 4*(l>>4)+j, col = lane&15
      if (grow < nrows) {
        float v = acc[j] + bb;
        SI[(long)grow * HD + col] = 1.f / (1.f + __expf(-v));
      }
    }
  }
}

// ------------------------------------------------ fused gather + epilogue
__global__ void __launch_bounds__(256) gather_finalize(const float* __restrict__ S,
                                                       const float* __restrict__ I,
                                                       const float* __restrict__ x3,
                                                       const int* __restrict__ off,
                                                       const int* __restrict__ ecol,
                                                       float* __restrict__ out,
                                                       int n_nodes) {
  int node = blockIdx.x * 4 + (threadIdx.x >> 6);
  if (node >= n_nodes) return;
  int lane = threadIdx.x & 63;

  int beg = off[node], end = off[node + 1];
  float2 acc = make_float2(0.f, 0.f);
  for (int j0 = beg; j0 < end; j0 += 64) {
    int myc = (j0 + lane < end) ? ecol[j0 + lane] : 0;
    int cnt = min(64, end - j0);
    int j = 0;
    for (; j + 3 < cnt; j += 4) {
      int c0 = __shfl(myc, j);
      int c1 = __shfl(myc, j + 1);
      int c2 = __shfl(myc, j + 2);
      int c3 = __shfl(myc, j + 3);
      float2 v0 = ((const float2*)(I + (long)c0 * HD))[lane];
      float2 v1 = ((const float2*)(I + (long)c1 * HD))[lane];
      float2 v2 = ((const float2*)(I + (long)c2 * HD))[lane];
      float2 v3 = ((const float2*)(I + (long)c3 * HD))[lane];
      acc.x += (v0.x + v1.x) + (v2.x + v3.x);
      acc.y += (v0.y + v1.y) + (v2.y + v3.y);
    }
    for (; j < cnt; ++j) {
      int c0 = __shfl(myc, j);
      float2 v0 = ((const float2*)(I + (long)c0 * HD))[lane];
      acc.x += v0.x;
      acc.y += v0.y;
    }
  }

  float beta  = x3[(long)node * HD + 0];
  float gamma = x3[(long)node * HD + 1];
  float2 s  = ((const float2*)(S + (long)node * HD))[lane];
  float2 ii = ((const float2*)(I + (long)node * HD))[lane];

  float2 dS, dI, dR;
  dS.x = -beta * acc.x * s.x;
  dS.y = -beta * acc.y * s.y;
  dI.x = -dS.x - gamma * ii.x;
  dI.y = -dS.y - gamma * ii.y;
  dR.x = gamma * ii.x;
  dR.y = gamma * ii.y;

  long p = (long)node * (HD / 2) + lane;
  long plane = (long)n_nodes * (HD / 2);
  float2* o = (float2*)out;
  o[p] = dS;
  o[plane + p] = dI;
  o[2 * plane + p] = dR;
  o[3 * plane + p] = make_float2(0.f, 0.f);   // zero plane 3 here
}

// ---------------------------------------------------------------- launcher
extern "C" void kernel_launch(void* const* d_in, const int* in_sizes, int n_in,
                              void* d_out, int out_size, void* d_ws, size_t ws_size,
                              hipStream_t stream) {
  const float* x = (const float*)d_in[0];
  const float* W = (const float*)d_in[1];
  const float* b = (const float*)d_in[2];
  const int* rows = (const int*)d_in[3];
  const int* cols = (const int*)d_in[4];
  float* out = (float*)d_out;

  int n_nodes = in_sizes[0] / (4 * HD);
  int n_edges = in_sizes[3];
  int nrows = 2 * n_nodes;

  // workspace layout
  float* S = (float*)d_ws;                       // n_nodes*HD floats
  float* I = S + (long)n_nodes * HD;             // n_nodes*HD floats
  int* ib = (int*)(I + (long)n_nodes * HD);      // int region (16B aligned)
  int npad = (n_nodes + 11) & ~3;                // >= n_nodes+8, mult of 4
  int* counts  = ib;                             // npad
  int* cursor  = counts + npad;                  // npad
  int* offsets = cursor + npad;                  // npad (needs n_nodes+1)
  int* bsum    = offsets + npad;                 // 256
  int* ecol    = bsum + 256;                     // n_edges

  // zero counts+cursor (contiguous 2*npad ints)
  zero_kernel<<<(2 * npad / 4 + 255) / 256, 256, 0, stream>>>(
      (float4*)counts, 2 * npad / 4);

  // histogram of destination rows
  hist_rows<<<512, 256, 0, stream>>>(rows, counts, n_edges);

  // scan counts -> offsets (2 kernels; scan_add derives its base in-block)
  int nb = (n_nodes + SCAN_E - 1) / SCAN_E;
  scan_block<<<nb, 256, 0, stream>>>(counts, offsets, bsum, n_nodes);
  scan_add<<<nb, 256, 0, stream>>>(offsets, bsum, nb, n_nodes, n_edges);

  // fused: CSR fill || SI = sigmoid(x[:2] @ W^T + b)
  int gblocks = (nrows + BM - 1) / BM;
  int fblocks = 192;
  fill_gemm<<<fblocks + gblocks, 512, 0, stream>>>(
      x, W, b, S, nrows, rows, cols, offsets, cursor, ecol, n_edges, fblocks);

  // fused gather + epilogue (writes all 4 out planes)
  int gfb = (n_nodes + 3) / 4;
  gather_finalize<<<gfb, 256, 0, stream>>>(S, I, x + 3 * (long)n_nodes * HD,
                                           offsets, ecol, out, n_nodes);
}